// Round 8
// baseline (955.170 us; speedup 1.0000x reference)
//
#include <hip/hip_runtime.h>
#include <hip/hip_fp16.h>
#include <stdint.h>

#define K_DIM 4096
#define N_DIM 11008
#define WPR   512            // packed int32 words per output row
#define NGRP  32             // quant groups per row

typedef _Float16 half8 __attribute__((ext_vector_type(8)));
typedef float floatx16 __attribute__((ext_vector_type(16)));
typedef float floatx4 __attribute__((ext_vector_type(4)));
union H8 { __half2 h2[4]; half8 v; };

#define GLOAD16(g, l) __builtin_amdgcn_global_load_lds( \
    (const __attribute__((address_space(1))) uint32_t*)(g), \
    (__attribute__((address_space(3))) uint32_t*)(l), 16, 0, 0)

// ============ fragment-major layout for mfma_f32_32x32x16 ============
// 16B unit u = blk32*16384 + (kh>>1)*64 + (kh&1)*32 + r
//   blk32 = row/32 (or col/32), kh = k/8 (0..511), r = row&31
// halves within a unit: (e0,e4,e1,e5,e2,e6,e3,e7) of k-chunk kh
// (A and B share the permutation -> dot products unaffected).

// ---------- pre-pass 1: x f32 -> f16 fragment-major
__global__ __launch_bounds__(256)
void cvt_x2(const float* __restrict__ x, _Float16* __restrict__ xh) {
    const size_t i = (size_t)blockIdx.x * 256 + threadIdx.x;
    const int r  = (int)i & 31;
    const int kh = ((int)(i >> 5)) & 511;
    const int mb = (int)(i >> 14);
    const float4* p = (const float4*)(x + ((size_t)mb * 32 + r) * K_DIM + kh * 8);
    float4 a = p[0], b = p[1];
    H8 h;
    h.h2[0] = __floats2half2_rn(a.x, b.x);
    h.h2[1] = __floats2half2_rn(a.y, b.y);
    h.h2[2] = __floats2half2_rn(a.z, b.z);
    h.h2[3] = __floats2half2_rn(a.w, b.w);
    const size_t u = (size_t)mb * 16384 + (size_t)((kh >> 1) * 64 + (kh & 1) * 32 + r);
    *(half8*)(xh + u * 8) = h.v;
}

// ---------- pre-pass 2: dequant W -> f16 fragment-major
__global__ __launch_bounds__(256)
void deq_w2(const uint32_t* __restrict__ qw, const float* __restrict__ scales,
            const float* __restrict__ biases, _Float16* __restrict__ wh) {
    const size_t i = (size_t)blockIdx.x * 256 + threadIdx.x;
    const int c  = (int)i & 31;
    const int w  = ((int)(i >> 5)) & 511;
    const int nb = (int)(i >> 14);
    const int row = nb * 32 + c;
    const uint32_t u = qw[(size_t)row * WPR + w];
    const int g = w >> 4;
    const __half2 s2 = __half2half2(__float2half(scales[(size_t)row * NGRP + g]));
    const __half2 b2 = __half2half2(__float2half(biases[(size_t)row * NGRP + g]));
    const __half2 c1024 = __float2half2_rn(1024.0f);
    H8 h;
    #pragma unroll
    for (int p = 0; p < 4; ++p) {
        const uint32_t v = ((u >> (4 * p)) & 0x000F000Fu) | 0x64006400u;
        const __half2 q2 = __hsub2(__builtin_bit_cast(__half2, v), c1024);
        h.h2[p] = __hfma2(s2, q2, b2);
    }
    const size_t uo = (size_t)nb * 16384 + (size_t)((w >> 1) * 64 + (w & 1) * 32 + c);
    *(half8*)(wh + uo * 8) = h.v;
}

// ---------- main GEMM: 256x128 tile, BK=32, 4 waves, 32x32x16 MFMA.
// Round-7 ledger (4-buf A via gload_lds, B direct->reg dbuf, stage-ahead-3)
// + 2-phase body interleave: each phase {4 ds_read || 2 stage || 2 B-load;
// bar; lgkm0; 8 MFMA; bar}. Counted vmcnt(16) once per body (in-order-safe).
__global__ __launch_bounds__(256, 2)
void qlin11(const _Float16* __restrict__ xh, const _Float16* __restrict__ wh,
            const float* __restrict__ linb, float* __restrict__ out)
{
    __shared__ _Float16 As[4][8192];    // 4 x 16 KB = 64 KB

    const int nwg = gridDim.x;
    int b = blockIdx.x;
    if ((nwg & 7) == 0) b = (b & 7) * (nwg >> 3) + (b >> 3);  // XCD swizzle
    const int NBN = N_DIM / 128;        // 86
    const int bn = b % NBN;             // bn fastest: consecutive blocks share A panel
    const int bm = b / NBN;

    const int tid  = threadIdx.x;
    const int lane = tid & 63;
    const int wid  = tid >> 6;          // 0..3
    const int wr   = wid >> 1;          // 0..1 -> 128-row half
    const int wc   = wid & 1;           // 0..1 -> 64-col slice

    // A staging: thread t stages LDS 16B-units t, t+256, t+512, t+768.
    const _Float16* aS0 = xh + ((size_t)(bm * 8 + (tid >> 7)) * 16384 + (size_t)(tid & 127)) * 8;
    const int ld0 = tid * 8;

    // B bases: wave's two 32-col blocks
    const _Float16* bB0 = wh + ((size_t)(bn * 4 + wc * 2) * 16384 + (size_t)lane) * 8;
    const _Float16* bB1 = bB0 + (size_t)16384 * 8;

    floatx16 acc[4][2] = {};
    half8 b0[4], b1[4];

    auto STG = [&](int kt, int qp) {                 // half qp of tile kt's staging
        const int k = (kt < 128) ? kt : 0;           // clamped tail (harmless rewrite)
        const size_t off = (size_t)k * 1024;
        #pragma unroll
        for (int q = 2 * qp; q < 2 * qp + 2; ++q)
            GLOAD16(aS0 + (size_t)(2 * q) * 16384 * 8 + off, &As[kt & 3][ld0 + q * 2048]);
    };
    auto LB = [&](half8* bq, int kt, int j) {        // B frags for col-block j
        const int k = (kt < 128) ? kt : 0;
        const _Float16* p = (j ? bB1 : bB0) + (size_t)k * 1024;
        bq[j * 2]     = *(const half8*)(p);
        bq[j * 2 + 1] = *(const half8*)(p + 512);
    };

    // one phase: i-pair {2p,2p+1} of body kt; vm<0 -> no vmcnt/no trailing barrier skip
    auto PHASE = [&](int kt, int p, const half8* bq, half8* bqn, int vm) {
        const _Float16* Ab = &As[kt & 3][0];
        half8 a[2][2];
        #pragma unroll
        for (int il = 0; il < 2; ++il)
            #pragma unroll
            for (int s = 0; s < 2; ++s)
                a[il][s] = *(const half8*)(Ab +
                    (size_t)(((wr * 4 + p * 2 + il) * 128 + s * 64 + lane) * 8));
        STG(kt + 3, p);          // 2 stage-issues
        LB(bqn, kt + 1, p);      // 2 B-loads (next body's col-block p)
        __builtin_amdgcn_s_barrier();
        asm volatile("s_waitcnt lgkmcnt(0)" ::: "memory");
        __builtin_amdgcn_sched_barrier(0);
        __builtin_amdgcn_s_setprio(1);
        #pragma unroll
        for (int s = 0; s < 2; ++s)
            #pragma unroll
            for (int il = 0; il < 2; ++il)
                #pragma unroll
                for (int j = 0; j < 2; ++j)
                    acc[p * 2 + il][j] = __builtin_amdgcn_mfma_f32_32x32x16_f16(
                        a[il][s], bq[j * 2 + s], acc[p * 2 + il][j], 0, 0, 0);
        __builtin_amdgcn_s_setprio(0);
        __builtin_amdgcn_sched_barrier(0);
        if (vm >= 0) asm volatile("s_waitcnt vmcnt(16)" ::: "memory");
        __builtin_amdgcn_s_barrier();
        __builtin_amdgcn_sched_barrier(0);
    };

    auto BODY = [&](int kt, const half8* bq, half8* bqn) {
        PHASE(kt, 0, bq, bqn, -1);
        PHASE(kt, 1, bq, bqn, 16);   // vmcnt(16): certifies stage(kt+1) [in-order]
    };

    // prologue: stage A tiles 0,1,2 (12 loads); load B(0) (4); drain once
    STG(0, 0); STG(0, 1); STG(1, 0); STG(1, 1); STG(2, 0); STG(2, 1);
    LB(b0, 0, 0); LB(b0, 0, 1);
    asm volatile("s_waitcnt vmcnt(0)" ::: "memory");
    __builtin_amdgcn_s_barrier();
    __builtin_amdgcn_sched_barrier(0);

    for (int kt = 0; kt < 128; kt += 2) {
        BODY(kt, b0, b1);
        BODY(kt + 1, b1, b0);
    }

    // epilogue: 32x32 C/D layout col = lane&31, row = (reg&3)+8*(reg>>2)+4*(lane>>5)
    const int colb = bn * 128 + wc * 64 + (lane & 31);
    const int rowb = bm * 256 + wr * 128 + 4 * (lane >> 5);
    #pragma unroll
    for (int j = 0; j < 2; ++j) {
        const int col = colb + j * 32;
        const float lb = linb[col];
        #pragma unroll
        for (int i = 0; i < 4; ++i) {
            #pragma unroll
            for (int reg = 0; reg < 16; ++reg) {
                const int row = rowb + i * 32 + (reg & 3) + 8 * (reg >> 2);
                out[(size_t)row * N_DIM + col] = acc[i][j][reg] + lb;
            }
        }
    }
}

// ---------- fallback (round-3 verified): fused-dequant 128x128 2-phase ----------
#define BM 128
#define BN 128
#define BK 64
#define NKT (K_DIM / BK)

__global__ __launch_bounds__(256)
void cvt_x(const float* __restrict__ x, _Float16* __restrict__ xh) {
    size_t i = (size_t)blockIdx.x * blockDim.x + threadIdx.x;
    const float4* p = (const float4*)(x + i * 8);
    float4 a = p[0], b = p[1];
    H8 h;
    h.h2[0] = __floats2half2_rn(a.x, b.x);
    h.h2[1] = __floats2half2_rn(a.y, b.y);
    h.h2[2] = __floats2half2_rn(a.z, b.z);
    h.h2[3] = __floats2half2_rn(a.w, b.w);
    *(half8*)(xh + i * 8) = h.v;
}

__global__ __launch_bounds__(256, 2)
void qlin_f16(const _Float16* __restrict__ xh,
              const uint32_t* __restrict__ qw,
              const float* __restrict__ scales,
              const float* __restrict__ biases,
              const float* __restrict__ linb,
              float* __restrict__ out)
{
    __shared__ _Float16 Asf[2][BM * BK];
    __shared__ _Float16 Bsf[2][BN * BK];

    const int NBN = N_DIM / BN;
    const int bn = blockIdx.x % NBN;
    const int bm = blockIdx.x / NBN;
    const int tid  = threadIdx.x;
    const int lane = tid & 63;
    const int wv   = tid >> 6;
    const int wm   = (wv >> 1) * 64;
    const int wn   = (wv & 1) * 64;

    const int arow = wv * 32 + (lane >> 3);
    const int acs  = ((lane & 7) ^ ((lane >> 3) & 7)) * 8;
    const _Float16* aSrc = xh + (size_t)(bm * BM + arow) * K_DIM + acs;

    const int srow = tid >> 1;
    const int bsel = tid & 1;
    const uint32_t* qB = qw + (size_t)(bn * BN + srow) * WPR + bsel * 4;
    const float*    sB = scales + (size_t)(bn * BN + srow) * NGRP;
    const float*    bB = biases + (size_t)(bn * BN + srow) * NGRP;
    const int bwbase = srow * BK;
    const int bswz   = srow & 7;

    floatx4 acc[4][4] = {};
    uint4 q0, q1; float s0, b0, s1, b1;

    auto LOADB = [&](uint4& qr, float& s, float& bb, int kt) {
        qr = *(const uint4*)(qB + kt * 8);
        s = sB[kt >> 1]; bb = bB[kt >> 1];
    };
    auto GLOADA = [&](int buf, int kt) {
        const _Float16* sp = aSrc + (size_t)kt * BK;
        #pragma unroll
        for (int j = 0; j < 4; ++j)
            GLOAD16(sp + (size_t)j * 8 * K_DIM, &Asf[buf][wv * 2048 + j * 512]);
    };
    auto DEQ = [&](const uint4& qr, float sf, float bf, int buf) {
        const __half2 s2 = __half2half2(__float2half(sf));
        const __half2 b2 = __half2half2(__float2half(bf));
        const __half2 c1024 = __float2half2_rn(1024.0f);
        const uint32_t uws[4] = {qr.x, qr.y, qr.z, qr.w};
        #pragma unroll
        for (int wi = 0; wi < 4; ++wi) {
            const uint32_t u = uws[wi];
            H8 h;
            #pragma unroll
            for (int p = 0; p < 4; ++p) {
                const uint32_t v = ((u >> (4 * p)) & 0x000F000Fu) | 0x64006400u;
                const __half2 q2 = __hsub2(__builtin_bit_cast(__half2, v), c1024);
                h.h2[p] = __hfma2(s2, q2, b2);
            }
            const int c = bsel * 4 + wi;
            *(half8*)&Bsf[buf][bwbase + ((c ^ bswz) * 8)] = h.v;
        }
    };
    const int fr = lane & 15;
    const int kq = lane >> 4;
    auto COMPUTE = [&](int buf) {
        const _Float16* Ab = &Asf[buf][0];
        const _Float16* Bb = &Bsf[buf][0];
        #pragma unroll
        for (int ks = 0; ks < 2; ++ks) {
            half8 af[4], bf[4];
            const int csx = ks * 4 + kq;
            #pragma unroll
            for (int i = 0; i < 4; ++i) {
                const int r = wm + i * 16 + fr;
                af[i] = *(const half8*)(Ab + r * BK + ((csx ^ (r & 7)) * 8));
            }
            #pragma unroll
            for (int i = 0; i < 4; ++i) {
                const int r = wn + i * 16 + fr;
                bf[i] = *(const half8*)(Bb + r * BK + ((csx ^ (r & 7)) * 8));
            }
            #pragma unroll
            for (int mf = 0; mf < 4; ++mf)
                #pragma unroll
                for (int nf = 0; nf < 4; ++nf)
                    acc[mf][nf] = __builtin_amdgcn_mfma_f32_16x16x32_f16(
                        af[mf], bf[nf], acc[mf][nf], 0, 0, 0);
        }
    };

    LOADB(q0, s0, b0, 0);
    GLOADA(0, 0);
    DEQ(q0, s0, b0, 0);
    LOADB(q0, s0, b0, 1);
    __syncthreads();
    for (int kt = 0; kt < NKT; kt += 2) {
        GLOADA(1, kt + 1);
        if (kt + 2 < NKT) LOADB(q1, s1, b1, kt + 2);
        DEQ(q0, s0, b0, 1);
        COMPUTE(0);
        __syncthreads();
        if (kt + 2 < NKT) {
            GLOADA(0, kt + 2);
            if (kt + 3 < NKT) LOADB(q0, s0, b0, kt + 3);
            DEQ(q1, s1, b1, 0);
        }
        COMPUTE(1);
        if (kt + 2 < NKT) __syncthreads();
    }
    const int rb = bm * BM + wm + ((lane >> 4) << 2);
    const int cb = bn * BN + wn + (lane & 15);
    #pragma unroll
    for (int nf = 0; nf < 4; ++nf) {
        const int col = cb + nf * 16;
        const float lb = linb[col];
        #pragma unroll
        for (int mf = 0; mf < 4; ++mf) {
            const int row = rb + mf * 16;
            #pragma unroll
            for (int j = 0; j < 4; ++j)
                out[(size_t)(row + j) * N_DIM + col] = acc[mf][nf][j] + lb;
        }
    }
}

extern "C" void kernel_launch(void* const* d_in, const int* in_sizes, int n_in,
                              void* d_out, int out_size, void* d_ws, size_t ws_size,
                              hipStream_t stream) {
    const float*    x      = (const float*)d_in[0];
    const uint32_t* qw     = (const uint32_t*)d_in[1];
    const float*    scales = (const float*)d_in[2];
    const float*    biases = (const float*)d_in[3];
    const float*    linb   = (const float*)d_in[4];
    float*          out    = (float*)d_out;

    const int M = in_sizes[0] / K_DIM;                      // 8192
    const size_t needX = (size_t)M * K_DIM * sizeof(_Float16);
    const size_t needW = (size_t)N_DIM * K_DIM * sizeof(_Float16);

    if (ws_size >= needX + needW && (M % 256) == 0) {
        _Float16* xh = (_Float16*)d_ws;
        _Float16* wh = xh + (size_t)M * K_DIM;
        cvt_x2<<<(unsigned)((size_t)M * 512 / 256), 256, 0, stream>>>(x, xh);
        deq_w2<<<(unsigned)((size_t)N_DIM * 512 / 256), 256, 0, stream>>>(qw, scales, biases, wh);
        dim3 grid((M / 256) * (N_DIM / 128));               // 32*86 = 2752
        qlin11<<<grid, 256, 0, stream>>>(xh, wh, linb, out);
    } else if (ws_size >= needX && (M % BM) == 0) {
        _Float16* xh = (_Float16*)d_ws;
        cvt_x<<<(unsigned)((size_t)M * K_DIM / 8 / 256), 256, 0, stream>>>(x, xh);
        dim3 grid((M / BM) * (N_DIM / BN));
        qlin_f16<<<grid, 256, 0, stream>>>(xh, qw, scales, biases, linb, out);
    }
}

// Round 9
// 842.340 us; speedup vs baseline: 1.1339x; 1.1339x over previous
//
#include <hip/hip_runtime.h>
#include <hip/hip_fp16.h>
#include <stdint.h>

#define K_DIM 4096
#define N_DIM 11008
#define WPR   512            // packed int32 words per output row
#define NGRP  32             // quant groups per row
#define NKT32 128            // K-tiles of 32

typedef _Float16 half8 __attribute__((ext_vector_type(8)));
typedef float floatx16 __attribute__((ext_vector_type(16)));
typedef float floatx4 __attribute__((ext_vector_type(4)));
union H8 { __half2 h2[4]; half8 v; };

#define GLOAD16(g, l) __builtin_amdgcn_global_load_lds( \
    (const __attribute__((address_space(1))) uint32_t*)(g), \
    (__attribute__((address_space(3))) uint32_t*)(l), 16, 0, 0)

// ============ fragment-major layout for mfma_f32_32x32x16 ============
// 16B unit u = blk32*16384 + (kh>>1)*64 + (kh&1)*32 + r
//   blk32 = row/32 (or col/32), kh = k/8 (0..511), r = row&31
// halves within a unit: (e0,e4,e1,e5,e2,e6,e3,e7) of k-chunk kh
// (A and B share the permutation -> dot products unaffected).
// K-tile32 kt of blk b = 128 contiguous units at b*16384 + kt*128;
// kstep s (16 k): units [+s*64, +s*64+64) -> lane l reads unit +s*64+l.

// ---------- pre-pass 1: x f32 -> f16 fragment-major
__global__ __launch_bounds__(256)
void cvt_x2(const float* __restrict__ x, _Float16* __restrict__ xh) {
    const size_t i = (size_t)blockIdx.x * 256 + threadIdx.x;
    const int r  = (int)i & 31;
    const int kh = ((int)(i >> 5)) & 511;
    const int mb = (int)(i >> 14);
    const float4* p = (const float4*)(x + ((size_t)mb * 32 + r) * K_DIM + kh * 8);
    float4 a = p[0], b = p[1];
    H8 h;
    h.h2[0] = __floats2half2_rn(a.x, b.x);
    h.h2[1] = __floats2half2_rn(a.y, b.y);
    h.h2[2] = __floats2half2_rn(a.z, b.z);
    h.h2[3] = __floats2half2_rn(a.w, b.w);
    const size_t u = (size_t)mb * 16384 + (size_t)((kh >> 1) * 64 + (kh & 1) * 32 + r);
    *(half8*)(xh + u * 8) = h.v;
}

// ---------- pre-pass 2: dequant W -> f16 fragment-major
__global__ __launch_bounds__(256)
void deq_w2(const uint32_t* __restrict__ qw, const float* __restrict__ scales,
            const float* __restrict__ biases, _Float16* __restrict__ wh) {
    const size_t i = (size_t)blockIdx.x * 256 + threadIdx.x;
    const int c  = (int)i & 31;
    const int w  = ((int)(i >> 5)) & 511;
    const int nb = (int)(i >> 14);
    const int row = nb * 32 + c;
    const uint32_t u = qw[(size_t)row * WPR + w];
    const int g = w >> 4;
    const __half2 s2 = __half2half2(__float2half(scales[(size_t)row * NGRP + g]));
    const __half2 b2 = __half2half2(__float2half(biases[(size_t)row * NGRP + g]));
    const __half2 c1024 = __float2half2_rn(1024.0f);
    H8 h;
    #pragma unroll
    for (int p = 0; p < 4; ++p) {
        const uint32_t v = ((u >> (4 * p)) & 0x000F000Fu) | 0x64006400u;
        const __half2 q2 = __hsub2(__builtin_bit_cast(__half2, v), c1024);
        h.h2[p] = __hfma2(s2, q2, b2);
    }
    const size_t uo = (size_t)nb * 16384 + (size_t)((w >> 1) * 64 + (w & 1) * 32 + c);
    *(half8*)(wh + uo * 8) = h.v;
}

// ---------- main GEMM: 256x256 tile, BK=32, 8 waves, 32x32x16 MFMA.
// m201-faithful: BOTH operands via global_load_lds (no VGPR global loads in
// K-loop -> only hand-placed vmcnts). 4 LDS buffers (A 16KB + B 16KB each,
// 128 KB total), stage-ahead-3, kstep-phases (2/K-tile): each phase
// {6 ds_read || 2 stage-issues; bar; lgkm0; 8 MFMA; bar}, vmcnt(8)/K-tile.
__global__ __launch_bounds__(512, 2)
void qlin12(const _Float16* __restrict__ xh, const _Float16* __restrict__ wh,
            const float* __restrict__ linb, float* __restrict__ out)
{
    __shared__ _Float16 LD[4][16384];   // 4 x 32 KB (A: halves 0..8191, B: 8192..16383)

    const int nwg = gridDim.x;
    int b = blockIdx.x;
    if ((nwg & 7) == 0) b = (b & 7) * (nwg >> 3) + (b >> 3);  // XCD swizzle
    const int NBN = N_DIM / 256;        // 43
    const int bn = b % NBN;
    const int bm = b / NBN;

    const int tid  = threadIdx.x;
    const int lane = tid & 63;
    const int wid  = tid >> 6;          // 0..7
    const int wr   = wid >> 2;          // 0..1 -> 128-row half
    const int wc   = wid & 3;           // 0..3 -> 64-col slice

    // staging: wave wid stages its own blk (=wid) of A (phase 0) / B (phase 1);
    // issue j in {0,1}: LDS unit wid*128 + j*64 + lane <- global unit
    // (panel*8 + wid)*16384 + kt*128 + j*64 + lane. Lane-contiguous both sides.
    const _Float16* aSt = xh + ((size_t)(bm * 8 + wid) * 16384 + (size_t)lane) * 8;
    const _Float16* bSt = wh + ((size_t)(bn * 8 + wid) * 16384 + (size_t)lane) * 8;
    const int ldsW = wid * 1024;        // halves

    floatx16 acc[4][2] = {};

    auto STAGE_A = [&](int kt) {
        const int k = (kt < NKT32) ? kt : 0;        // clamped tail (harmless)
        const size_t off = (size_t)k * 1024;        // halves
        GLOAD16(aSt + off,       &LD[kt & 3][ldsW]);
        GLOAD16(aSt + off + 512, &LD[kt & 3][ldsW + 512]);
    };
    auto STAGE_B = [&](int kt) {
        const int k = (kt < NKT32) ? kt : 0;
        const size_t off = (size_t)k * 1024;
        GLOAD16(bSt + off,       &LD[kt & 3][8192 + ldsW]);
        GLOAD16(bSt + off + 512, &LD[kt & 3][8192 + ldsW + 512]);
    };

    // phase p = kstep: 6 ds_read + 2 stage-issues; bar; lgkm0; 8 MFMA; bar.
    // vm >= 0 -> s_waitcnt vmcnt(vm) before trailing barrier (tile kt+1 gate).
    auto PHASE = [&](int kt, int p, bool stage, int vm) {
        const _Float16* Lb = &LD[kt & 3][0];
        half8 a[4], bb[2];
        #pragma unroll
        for (int mf = 0; mf < 4; ++mf)
            a[mf] = *(const half8*)(Lb + (wr * 4 + mf) * 1024 + p * 512 + lane * 8);
        #pragma unroll
        for (int nf = 0; nf < 2; ++nf)
            bb[nf] = *(const half8*)(Lb + 8192 + (wc * 2 + nf) * 1024 + p * 512 + lane * 8);
        if (stage) { if (p == 0) STAGE_A(kt + 3); else STAGE_B(kt + 3); }
        __builtin_amdgcn_s_barrier();
        asm volatile("s_waitcnt lgkmcnt(0)" ::: "memory");
        __builtin_amdgcn_sched_barrier(0);
        __builtin_amdgcn_s_setprio(1);
        #pragma unroll
        for (int mf = 0; mf < 4; ++mf)
            #pragma unroll
            for (int nf = 0; nf < 2; ++nf)
                acc[mf][nf] = __builtin_amdgcn_mfma_f32_32x32x16_f16(
                    a[mf], bb[nf], acc[mf][nf], 0, 0, 0);
        __builtin_amdgcn_s_setprio(0);
        __builtin_amdgcn_sched_barrier(0);
        if (vm == 8)      asm volatile("s_waitcnt vmcnt(8)" ::: "memory");
        else if (vm == 4) asm volatile("s_waitcnt vmcnt(4)" ::: "memory");
        else if (vm == 0) asm volatile("s_waitcnt vmcnt(0)" ::: "memory");
        __builtin_amdgcn_s_barrier();
        __builtin_amdgcn_sched_barrier(0);
    };

    // prologue: stage tiles 0,1,2 (12 loads/wave); vmcnt(8) retires tile 0.
    STAGE_A(0); STAGE_B(0);
    STAGE_A(1); STAGE_B(1);
    STAGE_A(2); STAGE_B(2);
    asm volatile("s_waitcnt vmcnt(8)" ::: "memory");
    __builtin_amdgcn_s_barrier();
    __builtin_amdgcn_sched_barrier(0);

    int kt = 0;
    for (; kt < NKT32 - 3; ++kt) { PHASE(kt, 0, true, -1); PHASE(kt, 1, true, 8); }
    PHASE(kt, 0, false, -1); PHASE(kt, 1, false, 4); ++kt;   // NKT-3
    PHASE(kt, 0, false, -1); PHASE(kt, 1, false, 0); ++kt;   // NKT-2
    PHASE(kt, 0, false, -1); PHASE(kt, 1, false, -1);        // NKT-1

    // epilogue: 32x32 C/D layout col = lane&31, row = (reg&3)+8*(reg>>2)+4*(lane>>5)
    const int colb = bn * 256 + wc * 64 + (lane & 31);
    const int rowb = bm * 256 + wr * 128 + 4 * (lane >> 5);
    #pragma unroll
    for (int j = 0; j < 2; ++j) {
        const int col = colb + j * 32;
        const float lb = linb[col];
        #pragma unroll
        for (int i = 0; i < 4; ++i) {
            #pragma unroll
            for (int reg = 0; reg < 16; ++reg) {
                const int row = rowb + i * 32 + (reg & 3) + 8 * (reg >> 2);
                out[(size_t)row * N_DIM + col] = acc[i][j][reg] + lb;
            }
        }
    }
}

// ---------- fallback (round-3 verified): fused-dequant 128x128 2-phase ----------
#define BM 128
#define BN 128
#define BK 64
#define NKT (K_DIM / BK)

__global__ __launch_bounds__(256)
void cvt_x(const float* __restrict__ x, _Float16* __restrict__ xh) {
    size_t i = (size_t)blockIdx.x * blockDim.x + threadIdx.x;
    const float4* p = (const float4*)(x + i * 8);
    float4 a = p[0], b = p[1];
    H8 h;
    h.h2[0] = __floats2half2_rn(a.x, b.x);
    h.h2[1] = __floats2half2_rn(a.y, b.y);
    h.h2[2] = __floats2half2_rn(a.z, b.z);
    h.h2[3] = __floats2half2_rn(a.w, b.w);
    *(half8*)(xh + i * 8) = h.v;
}

__global__ __launch_bounds__(256, 2)
void qlin_f16(const _Float16* __restrict__ xh,
              const uint32_t* __restrict__ qw,
              const float* __restrict__ scales,
              const float* __restrict__ biases,
              const float* __restrict__ linb,
              float* __restrict__ out)
{
    __shared__ _Float16 Asf[2][BM * BK];
    __shared__ _Float16 Bsf[2][BN * BK];

    const int NBN = N_DIM / BN;
    const int bn = blockIdx.x % NBN;
    const int bm = blockIdx.x / NBN;
    const int tid  = threadIdx.x;
    const int lane = tid & 63;
    const int wv   = tid >> 6;
    const int wm   = (wv >> 1) * 64;
    const int wn   = (wv & 1) * 64;

    const int arow = wv * 32 + (lane >> 3);
    const int acs  = ((lane & 7) ^ ((lane >> 3) & 7)) * 8;
    const _Float16* aSrc = xh + (size_t)(bm * BM + arow) * K_DIM + acs;

    const int srow = tid >> 1;
    const int bsel = tid & 1;
    const uint32_t* qB = qw + (size_t)(bn * BN + srow) * WPR + bsel * 4;
    const float*    sB = scales + (size_t)(bn * BN + srow) * NGRP;
    const float*    bB = biases + (size_t)(bn * BN + srow) * NGRP;
    const int bwbase = srow * BK;
    const int bswz   = srow & 7;

    floatx4 acc[4][4] = {};
    uint4 q0, q1; float s0, b0, s1, b1;

    auto LOADB = [&](uint4& qr, float& s, float& bb, int kt) {
        qr = *(const uint4*)(qB + kt * 8);
        s = sB[kt >> 1]; bb = bB[kt >> 1];
    };
    auto GLOADA = [&](int buf, int kt) {
        const _Float16* sp = aSrc + (size_t)kt * BK;
        #pragma unroll
        for (int j = 0; j < 4; ++j)
            GLOAD16(sp + (size_t)j * 8 * K_DIM, &Asf[buf][wv * 2048 + j * 512]);
    };
    auto DEQ = [&](const uint4& qr, float sf, float bf, int buf) {
        const __half2 s2 = __half2half2(__float2half(sf));
        const __half2 b2 = __half2half2(__float2half(bf));
        const __half2 c1024 = __float2half2_rn(1024.0f);
        const uint32_t uws[4] = {qr.x, qr.y, qr.z, qr.w};
        #pragma unroll
        for (int wi = 0; wi < 4; ++wi) {
            const uint32_t u = uws[wi];
            H8 h;
            #pragma unroll
            for (int p = 0; p < 4; ++p) {
                const uint32_t v = ((u >> (4 * p)) & 0x000F000Fu) | 0x64006400u;
                const __half2 q2 = __hsub2(__builtin_bit_cast(__half2, v), c1024);
                h.h2[p] = __hfma2(s2, q2, b2);
            }
            const int c = bsel * 4 + wi;
            *(half8*)&Bsf[buf][bwbase + ((c ^ bswz) * 8)] = h.v;
        }
    };
    const int fr = lane & 15;
    const int kq = lane >> 4;
    auto COMPUTE = [&](int buf) {
        const _Float16* Ab = &Asf[buf][0];
        const _Float16* Bb = &Bsf[buf][0];
        #pragma unroll
        for (int ks = 0; ks < 2; ++ks) {
            half8 af[4], bf[4];
            const int csx = ks * 4 + kq;
            #pragma unroll
            for (int i = 0; i < 4; ++i) {
                const int r = wm + i * 16 + fr;
                af[i] = *(const half8*)(Ab + r * BK + ((csx ^ (r & 7)) * 8));
            }
            #pragma unroll
            for (int i = 0; i < 4; ++i) {
                const int r = wn + i * 16 + fr;
                bf[i] = *(const half8*)(Bb + r * BK + ((csx ^ (r & 7)) * 8));
            }
            #pragma unroll
            for (int mf = 0; mf < 4; ++mf)
                #pragma unroll
                for (int nf = 0; nf < 4; ++nf)
                    acc[mf][nf] = __builtin_amdgcn_mfma_f32_16x16x32_f16(
                        af[mf], bf[nf], acc[mf][nf], 0, 0, 0);
        }
    };

    LOADB(q0, s0, b0, 0);
    GLOADA(0, 0);
    DEQ(q0, s0, b0, 0);
    LOADB(q0, s0, b0, 1);
    __syncthreads();
    for (int kt = 0; kt < NKT; kt += 2) {
        GLOADA(1, kt + 1);
        if (kt + 2 < NKT) LOADB(q1, s1, b1, kt + 2);
        DEQ(q0, s0, b0, 1);
        COMPUTE(0);
        __syncthreads();
        if (kt + 2 < NKT) {
            GLOADA(0, kt + 2);
            if (kt + 3 < NKT) LOADB(q0, s0, b0, kt + 3);
            DEQ(q1, s1, b1, 0);
        }
        COMPUTE(1);
        if (kt + 2 < NKT) __syncthreads();
    }
    const int rb = bm * BM + wm + ((lane >> 4) << 2);
    const int cb = bn * BN + wn + (lane & 15);
    #pragma unroll
    for (int nf = 0; nf < 4; ++nf) {
        const int col = cb + nf * 16;
        const float lb = linb[col];
        #pragma unroll
        for (int mf = 0; mf < 4; ++mf) {
            const int row = rb + mf * 16;
            #pragma unroll
            for (int j = 0; j < 4; ++j)
                out[(size_t)(row + j) * N_DIM + col] = acc[mf][nf][j] + lb;
        }
    }
}

extern "C" void kernel_launch(void* const* d_in, const int* in_sizes, int n_in,
                              void* d_out, int out_size, void* d_ws, size_t ws_size,
                              hipStream_t stream) {
    const float*    x      = (const float*)d_in[0];
    const uint32_t* qw     = (const uint32_t*)d_in[1];
    const float*    scales = (const float*)d_in[2];
    const float*    biases = (const float*)d_in[3];
    const float*    linb   = (const float*)d_in[4];
    float*          out    = (float*)d_out;

    const int M = in_sizes[0] / K_DIM;                      // 8192
    const size_t needX = (size_t)M * K_DIM * sizeof(_Float16);
    const size_t needW = (size_t)N_DIM * K_DIM * sizeof(_Float16);

    if (ws_size >= needX + needW && (M % 256) == 0) {
        _Float16* xh = (_Float16*)d_ws;
        _Float16* wh = xh + (size_t)M * K_DIM;
        cvt_x2<<<(unsigned)((size_t)M * 512 / 256), 256, 0, stream>>>(x, xh);
        deq_w2<<<(unsigned)((size_t)N_DIM * 512 / 256), 256, 0, stream>>>(qw, scales, biases, wh);
        dim3 grid((M / 256) * (N_DIM / 256));               // 32*43 = 1376
        qlin12<<<grid, 512, 0, stream>>>(xh, wh, linb, out);
    } else if (ws_size >= needX && (M % BM) == 0) {
        _Float16* xh = (_Float16*)d_ws;
        cvt_x<<<(unsigned)((size_t)M * K_DIM / 8 / 256), 256, 0, stream>>>(x, xh);
        dim3 grid((M / BM) * (N_DIM / BN));
        qlin_f16<<<grid, 256, 0, stream>>>(xh, qw, scales, biases, linb, out);
    }
}